// Round 9
// baseline (523.144 us; speedup 1.0000x reference)
//
#include <hip/hip_runtime.h>
#include <hip/hip_bf16.h>
#include <math.h>

#define N_NODES 8192
#define N_EDGES 262144
#define EP (N_EDGES + N_NODES)   // 270336 edges incl. self-loops
#define SLOPE 0.2f

typedef short bf16x8 __attribute__((ext_vector_type(8)));   // 8 bf16 in 4 VGPRs
typedef short short4v __attribute__((ext_vector_type(4)));
typedef unsigned short u16x8 __attribute__((ext_vector_type(8)));
typedef float f32x4 __attribute__((ext_vector_type(4)));

// ---------------------------------------------------------------- merged prologue
// One dispatch: split3(x) -> A3, all-layer W3 prep, and edge histogram.
// Ranges are block-aligned (2048 / 1280 / 1024 blocks) so branches are block-uniform.
struct WPrep {
    const float* wl[5];
    const float* wr[5];
    int oc[5];
    int lk[5];
};

__global__ void prologue(WPrep P, const float* __restrict__ x,
                         short* __restrict__ W3all, short* __restrict__ A3,
                         const int* __restrict__ raw, int* __restrict__ counts) {
    __shared__ int sflag;
    int gid = blockIdx.x * blockDim.x + threadIdx.x;
    if (gid < 524288) {              // split3 of x: [8192,256] -> A3 [8192,768]
        int r = gid >> 6;
        int c4 = (gid & 63) << 2;
        f32x4 a = *(const f32x4*)&x[((size_t)r << 8) + c4];
        short4v h4, l4;
#pragma unroll
        for (int j = 0; j < 4; ++j) {
            __hip_bfloat16 hb = __float2bfloat16(a[j]);
            float hf = __bfloat162float(hb);
            __hip_bfloat16 lb = __float2bfloat16(a[j] - hf);
            h4[j] = *(short*)&hb;
            l4[j] = *(short*)&lb;
        }
        size_t ro = (size_t)r * 768;
        *(short4v*)&A3[ro + c4] = h4;
        *(short4v*)&A3[ro + 256 + c4] = l4;
        *(short4v*)&A3[ro + 512 + c4] = h4;
    } else if (gid < 851968) {       // weight prep: W3 = [hi|hi|lo] of [wl;wr]
        int g = gid - 524288;
        int l = g >> 16;
        int rem = g & 65535;
        int lk = P.lk[l], K = 1 << lk;
        int r = rem >> lk, c = rem & (K - 1);
        int OC = P.oc[l];
        const float* w = (r < OC) ? P.wl[l] : P.wr[l];
        int rr = (r < OC) ? r : r - OC;
        float a = w[((size_t)rr << lk) + c];
        __hip_bfloat16 hb = __float2bfloat16(a);
        float hf = __bfloat162float(hb);
        __hip_bfloat16 lb = __float2bfloat16(a - hf);
        size_t ro = (size_t)l * 196608 + (size_t)r * 3 * K;
        W3all[ro + c] = *(short*)&hb;
        W3all[ro + K + c] = *(short*)&hb;
        W3all[ro + 2 * K + c] = *(short*)&lb;
    } else {                         // histogram (with per-block i64 detect)
        int t = threadIdx.x;
        if (t < 64) {
            unsigned long long b = __ballot(raw[2 * t + 1] != 0);
            if (t == 0) sflag = (b == 0ULL) ? 1 : 0;
        }
        __syncthreads();
        int k = gid - 851968;        // [0, 262144)
        int d = sflag ? raw[2 * ((size_t)N_EDGES + k)] : raw[N_EDGES + k];
        atomicAdd(&counts[d], 1);
    }
}

// ---------------------------------------------------------------- scan (coalesced load)
__global__ void scan_k(const int* __restrict__ counts, int* __restrict__ row_ptr) {
    __shared__ int buf[8192];
    __shared__ int part[256];
    int t = threadIdx.x;
    for (int i = 0; i < 32; ++i) buf[i * 256 + t] = counts[i * 256 + t];
    __syncthreads();
    int base = t * 32;
    int loc[32];
    int s = 0;
    for (int i = 0; i < 32; ++i) { loc[i] = s; s += buf[base + i] + 1; }  // +1 self-loop
    part[t] = s;
    __syncthreads();
    for (int off = 1; off < 256; off <<= 1) {
        int tmp = (t >= off) ? part[t - off] : 0;
        __syncthreads();
        part[t] += tmp;
        __syncthreads();
    }
    int incl = part[t];
    int excl = incl - s;
    for (int i = 0; i < 32; ++i) row_ptr[base + i] = excl + loc[i];
    if (t == 255) row_ptr[N_NODES] = incl;
}

// ---------------------------------------------------------------- scatter (re-decodes raw)
__global__ void scatter_k(const int* __restrict__ raw, const int* __restrict__ row_ptr,
                          int* __restrict__ cursor, int* __restrict__ ssrc) {
    __shared__ int sflag;
    int t = threadIdx.x;
    if (t < 64) {
        unsigned long long b = __ballot(raw[2 * t + 1] != 0);
        if (t == 0) sflag = (b == 0ULL) ? 1 : 0;
    }
    __syncthreads();
    int k = blockIdx.x * blockDim.x + t;
    if (k >= EP) return;
    int s, d;
    if (k < N_EDGES) {
        if (sflag) { s = raw[2 * (size_t)k]; d = raw[2 * ((size_t)N_EDGES + k)]; }
        else       { s = raw[k]; d = raw[N_EDGES + k]; }
    } else s = d = k - N_EDGES;
    int pos = row_ptr[d] + atomicAdd(&cursor[d], 1);
    ssrc[pos] = s;
}

// ---------------------------------------------------------------- global_load_lds helper
#if __has_builtin(__builtin_amdgcn_global_load_lds)
#define GL16(gsrc, lbase, lofs)                                                       \
    __builtin_amdgcn_global_load_lds((const __attribute__((address_space(1))) void*)(gsrc), \
                                     (__attribute__((address_space(3))) void*)(lbase), 16, 0, 0)
#else
#define GL16(gsrc, lbase, lofs) (*(bf16x8*)((lbase) + (lofs)) = *(const bf16x8*)(gsrc))
#endif

// ---------------------------------------------------------------- GEMM body (shared by 2 kernels)
// C = A3[8192,K3].W3[:,K3]^T for one 64x64 tile; epilogue slab-splits cols into
// XLb (bf16 gather buf) / XRf (f32). dbuf LDS (uses SH[0..16383] shorts); counted vmcnt(4).
__device__ __forceinline__ void gemm_body(const short* __restrict__ A3, const short* __restrict__ W3,
                                          unsigned short* __restrict__ XLb, float* __restrict__ XRf,
                                          int K3, int ocl, int lgpl,
                                          int bx, int by, short* SH) {
    int tid = threadIdx.x;
    int i0 = by * 64, j0 = bx * 64;
    int wave = tid >> 6, lane = tid & 63;
    int b0 = wave * 1024 + lane * 16;
    int row0 = b0 >> 7;
    int rb0 = b0 & 127;
    int scb = rb0 ^ ((row0 & 7) << 4);
    const short* gA0 = A3 + (size_t)(i0 + row0) * K3 + (scb >> 1);
    const short* gA1 = A3 + (size_t)(i0 + row0 + 32) * K3 + (scb >> 1);
    const short* gB0 = W3 + (size_t)(j0 + row0) * K3 + (scb >> 1);
    const short* gB1 = W3 + (size_t)(j0 + row0 + 32) * K3 + (scb >> 1);
    int lofs = lane * 8;

#define STAGE(pb, k0s)                                      \
    do {                                                    \
        short* Ad = SH + (pb) * 4096;                       \
        short* Bd = SH + 8192 + (pb) * 4096;                \
        GL16(gA0 + (k0s), Ad + wave * 512, lofs);           \
        GL16(gA1 + (k0s), Ad + 2048 + wave * 512, lofs);    \
        GL16(gB0 + (k0s), Bd + wave * 512, lofs);           \
        GL16(gB1 + (k0s), Bd + 2048 + wave * 512, lofs);    \
    } while (0)

    int wr = (wave >> 1) * 32, wc = (wave & 1) * 32;
    int lm = lane & 15, quad = lane >> 4;
    f32x4 acc[2][2] = {};
    int nt = K3 >> 6;
    STAGE(0, 0);
    int cur = 0;
    for (int t = 0; t < nt; ++t) {
        if (t + 1 < nt) {
            STAGE(cur ^ 1, (t + 1) << 6);
            asm volatile("s_waitcnt vmcnt(4)" ::: "memory");
        } else {
            asm volatile("s_waitcnt vmcnt(0)" ::: "memory");
        }
        __builtin_amdgcn_s_barrier();
        __builtin_amdgcn_sched_barrier(0);
        const char* Ab = (const char*)(SH + cur * 4096);
        const char* Bb = (const char*)(SH + 8192 + cur * 4096);
#pragma unroll
        for (int ks = 0; ks < 2; ++ks) {
            int kb = ks * 64 + quad * 16;
            bf16x8 a[2], b[2];
#pragma unroll
            for (int u = 0; u < 2; ++u) {
                int r = wr + u * 16 + lm;
                a[u] = *(const bf16x8*)(Ab + (((r << 7) | kb) ^ ((r & 7) << 4)));
            }
#pragma unroll
            for (int v = 0; v < 2; ++v) {
                int r = wc + v * 16 + lm;
                b[v] = *(const bf16x8*)(Bb + (((r << 7) | kb) ^ ((r & 7) << 4)));
            }
#pragma unroll
            for (int u = 0; u < 2; ++u)
#pragma unroll
                for (int v = 0; v < 2; ++v)
                    acc[u][v] = __builtin_amdgcn_mfma_f32_16x16x32_bf16(a[u], b[v], acc[u][v], 0, 0, 0);
        }
        __builtin_amdgcn_sched_barrier(0);
        __builtin_amdgcn_s_barrier();
        cur ^= 1;
    }
#undef STAGE
    // C/D layout: col = lane&15, row = quad*4 + reg (m89/m91-verified)
    int plm = (1 << lgpl) - 1;
#pragma unroll
    for (int u = 0; u < 2; ++u)
#pragma unroll
        for (int v = 0; v < 2; ++v)
#pragma unroll
            for (int r = 0; r < 4; ++r) {
                int row = i0 + wr + u * 16 + quad * 4 + r;
                int col = j0 + wc + v * 16 + lm;
                int slab = col >> lgpl;
                int wn = col & plm;
                float val = acc[u][v][r];
                size_t base = (size_t)slab * N_NODES * ocl + (size_t)row * ocl;
                if (wn < ocl) {
                    __hip_bfloat16 hb = __float2bfloat16(val);
                    XLb[base + wn] = *(unsigned short*)&hb;
                } else {
                    XRf[base + wn - ocl] = val;
                }
            }
}

// standalone GEMM (1D grid, XCD swizzle)
__global__ __launch_bounds__(256) void gemm_std(const short* __restrict__ A3,
                                                const short* __restrict__ W3,
                                                unsigned short* __restrict__ XLb,
                                                float* __restrict__ XRf,
                                                int K3, int ocl, int lgpl, int lgx) {
    __shared__ __align__(16) short SH[16384];
    int nwg = gridDim.x;
    int orig = blockIdx.x;
    int swzb = (orig & 7) * (nwg >> 3) + (orig >> 3);
    int bx = swzb & ((1 << lgx) - 1), by = swzb >> lgx;
    gemm_body(A3, W3, XLb, XRf, K3, ocl, lgpl, bx, by, SH);
}

// ---------------------------------------------------------------- recon 64x64-tile body
// One upper-triangle tile s of sigmoid(R.R^T); mirrors off-diagonal via LDS transpose.
// Uses SH[0..17407] shorts (As/Bs), reused as f32 [64][65] for transpose. NT stores.
__device__ __forceinline__ void recon64_body(int s, const unsigned short* __restrict__ Rb,
                                             float* __restrict__ C, short* SH) {
    // decode triangular index: start(bi) = bi*(257-bi)/2 over n=128 tile-rows
    float ff = 128.5f - sqrtf(128.5f * 128.5f - 2.0f * (float)s);
    int bi = (int)ff;
    if (bi < 0) bi = 0;
    if (bi > 127) bi = 127;
    while (bi > 0 && (bi * (257 - bi)) / 2 > s) --bi;
    while (((bi + 1) * (257 - (bi + 1))) / 2 <= s) ++bi;
    int bj = bi + (s - (bi * (257 - bi)) / 2);
    int i0 = bi * 64, j0 = bj * 64;
    short* As = SH;
    short* Bs = SH + 64 * 136;
    const short* R = (const short*)Rb;
    int tid = threadIdx.x;
#pragma unroll
    for (int c = 0; c < 4; ++c) {    // 64 rows x 128 bf16 = 1024 16B-chunks per panel
        int idx = tid + c * 256;
        int row = idx >> 4, col = (idx & 15) * 8;
        *(bf16x8*)(&As[row * 136 + col]) = *(const bf16x8*)(&R[(size_t)(i0 + row) * 128 + col]);
        *(bf16x8*)(&Bs[row * 136 + col]) = *(const bf16x8*)(&R[(size_t)(j0 + row) * 128 + col]);
    }
    __syncthreads();
    int wave = tid >> 6, lane = tid & 63;
    int wr = (wave >> 1) * 32, wc = (wave & 1) * 32;
    int lm = lane & 15, quad = lane >> 4;
    f32x4 acc[2][2] = {};
#pragma unroll
    for (int ks = 0; ks < 4; ++ks) {
        int ko = ks * 32 + quad * 8;
        bf16x8 a[2], b[2];
#pragma unroll
        for (int u = 0; u < 2; ++u)
            a[u] = *(const bf16x8*)(&As[(wr + u * 16 + lm) * 136 + ko]);
#pragma unroll
        for (int v = 0; v < 2; ++v)
            b[v] = *(const bf16x8*)(&Bs[(wc + v * 16 + lm) * 136 + ko]);
#pragma unroll
        for (int u = 0; u < 2; ++u)
#pragma unroll
            for (int v = 0; v < 2; ++v)
                acc[u][v] = __builtin_amdgcn_mfma_f32_16x16x32_bf16(a[u], b[v], acc[u][v], 0, 0, 0);
    }
    // sigmoid + direct write; stash for mirror
#pragma unroll
    for (int u = 0; u < 2; ++u)
#pragma unroll
        for (int v = 0; v < 2; ++v)
#pragma unroll
            for (int r = 0; r < 4; ++r) {
                float sg = 1.0f / (1.0f + __expf(-acc[u][v][r]));
                acc[u][v][r] = sg;
                int row = i0 + wr + u * 16 + quad * 4 + r;
                int col = j0 + wc + v * 16 + lm;
                __builtin_nontemporal_store(sg, &C[(size_t)row * 8192 + col]);
            }
    if (bi != bj) {
        __syncthreads();
        float* T = (float*)SH;   // [64][65]
#pragma unroll
        for (int u = 0; u < 2; ++u)
#pragma unroll
            for (int v = 0; v < 2; ++v)
#pragma unroll
                for (int r = 0; r < 4; ++r)
                    T[(wr + u * 16 + quad * 4 + r) * 65 + (wc + v * 16 + lm)] = acc[u][v][r];
        __syncthreads();
#pragma unroll
        for (int it = 0; it < 16; ++it) {
            int idx = tid + it * 256;
            int rp = idx >> 6, cp = idx & 63;
            __builtin_nontemporal_store(T[cp * 65 + rp], &C[(size_t)(j0 + rp) * 8192 + (i0 + cp)]);
        }
    }
}

// combined: l4 GEMM (blocks 0..1023) + recon half A (blocks 1024..5151)
__global__ __launch_bounds__(256) void gemm_recon(const short* __restrict__ A3,
                                                  const short* __restrict__ W3,
                                                  unsigned short* __restrict__ XLb,
                                                  float* __restrict__ XRf,
                                                  int K3, int ocl, int lgpl,
                                                  const unsigned short* __restrict__ Rb,
                                                  float* __restrict__ C, int sbase) {
    __shared__ __align__(16) short SH[17408];
    int id = blockIdx.x;
    if (id < 1024) {
        int swzb = (id & 7) * 128 + (id >> 3);
        gemm_body(A3, W3, XLb, XRf, K3, ocl, lgpl, swzb & 7, swzb >> 3, SH);
    } else {
        int orig = id - 1024;                       // 4128 = 8*516: bijective XCD swizzle
        int s = (orig & 7) * 516 + (orig >> 3) + sbase;
        recon64_body(s, Rb, C, SH);
    }
}

// ---------------------------------------------------------------- GAT (no-max softmax, bf16 gathers)
struct GatP {
    const float* att; const float* bias;
    float* outf; short* a3; unsigned short* rb;
    const unsigned short* xlb; const float* xrf;
};

__device__ __forceinline__ void cvt8(u16x8 w, float* v) {
#pragma unroll
    for (int j = 0; j < 8; ++j) v[j] = __uint_as_float(((unsigned)w[j]) << 16);
}

// OC=128; dual-layer dispatch: block >= 8192 -> P1. (unchanged from R8)
__global__ __launch_bounds__(256) void gat128(const int* __restrict__ row_ptr,
                                              const int* __restrict__ ssrc,
                                              GatP P0, GatP P1) {
    __shared__ float sacc[16][128];
    __shared__ float ss[16];
    int d = blockIdx.x & (N_NODES - 1);
    GatP P = (blockIdx.x >= N_NODES) ? P1 : P0;
    int t = threadIdx.x, ln = t & 15, g = t >> 4;
    int beg = row_ptr[d], end = row_ptr[d + 1];
    float xr[8], at[8];
    {
        f32x4 a0 = *(const f32x4*)&P.xrf[(size_t)d * 128 + ln * 8];
        f32x4 a1 = *(const f32x4*)&P.xrf[(size_t)d * 128 + ln * 8 + 4];
        f32x4 b0 = *(const f32x4*)&P.att[ln * 8];
        f32x4 b1 = *(const f32x4*)&P.att[ln * 8 + 4];
#pragma unroll
        for (int j = 0; j < 4; ++j) { xr[j] = a0[j]; xr[4 + j] = a1[j]; at[j] = b0[j]; at[4 + j] = b1[j]; }
    }
    float s = 0.0f, acc[8] = {};
    int p = beg + g;
    for (; p + 16 < end; p += 32) {
        int s0 = ssrc[p], s1 = ssrc[p + 16];
        float v0[8], v1[8];
        cvt8(*(const u16x8*)&P.xlb[(size_t)s0 * 128 + ln * 8], v0);
        cvt8(*(const u16x8*)&P.xlb[(size_t)s1 * 128 + ln * 8], v1);
        float e0 = 0.0f, e1 = 0.0f;
#pragma unroll
        for (int j = 0; j < 8; ++j) {
            float u0 = v0[j] + xr[j]; u0 = (u0 > 0.0f) ? u0 : SLOPE * u0; e0 += u0 * at[j];
            float u1 = v1[j] + xr[j]; u1 = (u1 > 0.0f) ? u1 : SLOPE * u1; e1 += u1 * at[j];
        }
#pragma unroll
        for (int off = 8; off; off >>= 1) {
            e0 += __shfl_xor(e0, off, 64);
            e1 += __shfl_xor(e1, off, 64);
        }
        float q0 = __expf(e0), q1 = __expf(e1);
        s += q0 + q1;
#pragma unroll
        for (int j = 0; j < 8; ++j) acc[j] += q0 * v0[j] + q1 * v1[j];
    }
    if (p < end) {
        int si = ssrc[p];
        float v[8];
        cvt8(*(const u16x8*)&P.xlb[(size_t)si * 128 + ln * 8], v);
        float e = 0.0f;
#pragma unroll
        for (int j = 0; j < 8; ++j) {
            float u = v[j] + xr[j];
            u = (u > 0.0f) ? u : SLOPE * u;
            e += u * at[j];
        }
#pragma unroll
        for (int off = 8; off; off >>= 1) e += __shfl_xor(e, off, 64);
        float q = __expf(e);
        s += q;
#pragma unroll
        for (int j = 0; j < 8; ++j) acc[j] += q * v[j];
    }
#pragma unroll
    for (int j = 0; j < 8; ++j) sacc[g][ln * 8 + j] = acc[j];
    if (ln == 0) ss[g] = s;
    __syncthreads();
    if (t < 128) {
        float tot = 0.0f, st = 0.0f;
#pragma unroll
        for (int w = 0; w < 16; ++w) { tot += sacc[w][t]; st += ss[w]; }
        float val = fmaxf(tot / st + P.bias[t], 0.0f);
        if (P.outf) P.outf[(size_t)d * 128 + t] = val;
        if (P.a3) {
            __hip_bfloat16 hb = __float2bfloat16(val);
            float hf = __bfloat162float(hb);
            __hip_bfloat16 lb = __float2bfloat16(val - hf);
            size_t ro = (size_t)d * 384;
            P.a3[ro + t] = *(short*)&hb;
            P.a3[ro + 128 + t] = *(short*)&lb;
            P.a3[ro + 256 + t] = *(short*)&hb;
        }
        if (P.rb) {
            __hip_bfloat16 hb = __float2bfloat16(val);
            P.rb[d * 128 + t] = *(unsigned short*)&hb;
        }
    }
}

// OC=256 body (32 lanes/edge, 8 groups); sacc = [8*256] f32, ss = [8] f32 in LDS.
__device__ __forceinline__ void gat256_body(const int* __restrict__ row_ptr,
                                            const int* __restrict__ ssrc,
                                            const unsigned short* __restrict__ xlb,
                                            const float* __restrict__ xrf,
                                            const float* __restrict__ att,
                                            const float* __restrict__ bias,
                                            float* __restrict__ outf,
                                            short* __restrict__ a3,
                                            int d, float* sacc, float* ss) {
    int t = threadIdx.x;
    int ln = t & 31, g = t >> 5;
    int beg = row_ptr[d], end = row_ptr[d + 1];
    float xr[8], at[8];
    {
        f32x4 a0 = *(const f32x4*)&xrf[(size_t)d * 256 + ln * 8];
        f32x4 a1 = *(const f32x4*)&xrf[(size_t)d * 256 + ln * 8 + 4];
        f32x4 b0 = *(const f32x4*)&att[ln * 8];
        f32x4 b1 = *(const f32x4*)&att[ln * 8 + 4];
#pragma unroll
        for (int j = 0; j < 4; ++j) { xr[j] = a0[j]; xr[4 + j] = a1[j]; at[j] = b0[j]; at[4 + j] = b1[j]; }
    }
    float s = 0.0f, acc[8] = {};
    int p = beg + g;
    for (; p + 8 < end; p += 16) {
        int s0 = ssrc[p], s1 = ssrc[p + 8];
        float v0[8], v1[8];
        cvt8(*(const u16x8*)&xlb[(size_t)s0 * 256 + ln * 8], v0);
        cvt8(*(const u16x8*)&xlb[(size_t)s1 * 256 + ln * 8], v1);
        float e0 = 0.0f, e1 = 0.0f;
#pragma unroll
        for (int j = 0; j < 8; ++j) {
            float u0 = v0[j] + xr[j]; u0 = (u0 > 0.0f) ? u0 : SLOPE * u0; e0 += u0 * at[j];
            float u1 = v1[j] + xr[j]; u1 = (u1 > 0.0f) ? u1 : SLOPE * u1; e1 += u1 * at[j];
        }
#pragma unroll
        for (int off = 16; off; off >>= 1) {
            e0 += __shfl_xor(e0, off, 64);
            e1 += __shfl_xor(e1, off, 64);
        }
        float q0 = __expf(e0), q1 = __expf(e1);
        s += q0 + q1;
#pragma unroll
        for (int j = 0; j < 8; ++j) acc[j] += q0 * v0[j] + q1 * v1[j];
    }
    if (p < end) {
        int si = ssrc[p];
        float v[8];
        cvt8(*(const u16x8*)&xlb[(size_t)si * 256 + ln * 8], v);
        float e = 0.0f;
#pragma unroll
        for (int j = 0; j < 8; ++j) {
            float u = v[j] + xr[j];
            u = (u > 0.0f) ? u : SLOPE * u;
            e += u * at[j];
        }
#pragma unroll
        for (int off = 16; off; off >>= 1) e += __shfl_xor(e, off, 64);
        float q = __expf(e);
        s += q;
#pragma unroll
        for (int j = 0; j < 8; ++j) acc[j] += q * v[j];
    }
#pragma unroll
    for (int j = 0; j < 8; ++j) sacc[g * 256 + ln * 8 + j] = acc[j];
    if (ln == 0) ss[g] = s;
    __syncthreads();
    {
        float tot = 0.0f, st = 0.0f;
#pragma unroll
        for (int w = 0; w < 8; ++w) { tot += sacc[w * 256 + t]; st += ss[w]; }
        float val = fmaxf(tot / st + bias[t], 0.0f);
        if (outf) outf[(size_t)d * 256 + t] = val;
        if (a3) {
            __hip_bfloat16 hb = __float2bfloat16(val);
            float hf = __bfloat162float(hb);
            __hip_bfloat16 lb = __float2bfloat16(val - hf);
            size_t ro = (size_t)d * 768;
            a3[ro + t] = *(short*)&hb;
            a3[ro + 256 + t] = *(short*)&lb;
            a3[ro + 512 + t] = *(short*)&hb;
        }
    }
}

__global__ __launch_bounds__(256) void gat256(const int* __restrict__ row_ptr,
                                              const int* __restrict__ ssrc,
                                              const unsigned short* __restrict__ xlb,
                                              const float* __restrict__ xrf,
                                              const float* __restrict__ att,
                                              const float* __restrict__ bias,
                                              float* __restrict__ outf,
                                              short* __restrict__ a3) {
    __shared__ float SA[8 * 256 + 8];
    gat256_body(row_ptr, ssrc, xlb, xrf, att, bias, outf, a3, blockIdx.x, SA, SA + 8 * 256);
}

// combined: l4 GAT (blocks 0..8191) + recon half B (blocks 8192..12319)
__global__ __launch_bounds__(256) void gat256_recon(const int* __restrict__ row_ptr,
                                                    const int* __restrict__ ssrc,
                                                    const unsigned short* __restrict__ xlb,
                                                    const float* __restrict__ xrf,
                                                    const float* __restrict__ att,
                                                    const float* __restrict__ bias,
                                                    float* __restrict__ outf,
                                                    const unsigned short* __restrict__ Rb,
                                                    float* __restrict__ C, int sbase) {
    __shared__ __align__(16) short SH[17408];
    int id = blockIdx.x;
    if (id < N_NODES) {
        float* SA = (float*)SH;
        gat256_body(row_ptr, ssrc, xlb, xrf, att, bias, outf, nullptr, id, SA, SA + 8 * 256);
    } else {
        int orig = id - N_NODES;
        int s = (orig & 7) * 516 + (orig >> 3) + sbase;
        recon64_body(s, Rb, C, SH);
    }
}

// ---------------------------------------------------------------- host side
static inline int ceil_div(int a, int b) { return (a + b - 1) / b; }

extern "C" void kernel_launch(void* const* d_in, const int* in_sizes, int n_in,
                              void* d_out, int out_size, void* d_ws, size_t ws_size,
                              hipStream_t stream) {
    const float* x    = (const float*)d_in[0];
    const int*   eraw = (const int*)d_in[1];

    WPrep P;
    const float* att[5];
    const float* bia[5];
    for (int l = 0; l < 5; ++l) {
        P.wl[l] = (const float*)d_in[2 + 4 * l + 0];
        P.wr[l] = (const float*)d_in[2 + 4 * l + 1];
        att[l]  = (const float*)d_in[2 + 4 * l + 2];
        bia[l]  = (const float*)d_in[2 + 4 * l + 3];
    }
    const int och[5]  = {128, 256, 128, 128, 256};
    const int logK[5] = {8, 7, 8, 8, 7};
    for (int l = 0; l < 5; ++l) { P.oc[l] = och[l]; P.lk[l] = logK[l]; }

    float* outp  = (float*)d_out;
    float* recon = outp;                          // [8192, 8192]
    float* xrec  = outp + (size_t)67108864;       // [8192, 256]
    float* zout  = outp + (size_t)69206016;       // [8192, 256]

    // ---------------- workspace layout (f32 words); ~31 MB
    float* W = (float*)d_ws;
    unsigned short* XLb = (unsigned short*)W;             // 2,097,152 ushorts (4 MB)
    float* XRf   = W + 1048576;                           // 2,097,152 f32 (8 MB)
    short* A3    = (short*)(W + 3145728);                 // 6,291,456 shorts
    short* W3all = (short*)(W + 6291456);                 //   983,040 shorts
    unsigned short* Rb = (unsigned short*)(W + 6782976);  // 1,048,576 ushorts
    int* I       = (int*)(W + 7307264);
    int* counts  = I;                // 8192
    int* cursor  = I + 8192;         // 8192
    int* row_ptr = I + 16384;        // 8193
    int* ssrc    = I + 24577;        // 270336

    // ---------------- CSR build + prep (hist fused into prologue)
    hipMemsetAsync(counts, 0, 2 * 8192 * sizeof(int), stream);   // counts + cursor
    prologue<<<4352, 256, 0, stream>>>(P, x, W3all, A3, eraw, counts);
    scan_k<<<1, 256, 0, stream>>>(counts, row_ptr);
    scatter_k<<<ceil_div(EP, 256), 256, 0, stream>>>(eraw, row_ptr, cursor, ssrc);

    // ---- layer 0 (OC=128): gemm N2=256, gat -> A3 (stride 384)
    {
        gemm_std<<<512, 256, 0, stream>>>(A3, W3all + 0 * 196608, XLb, XRf, 768, 128, 8, 2);
        GatP g0{att[0], bia[0], nullptr, A3, nullptr, XLb, XRf};
        gat128<<<N_NODES, 256, 0, stream>>>(row_ptr, ssrc, g0, g0);
    }
    // ---- layer 1 (OC=256): gemm N2=512 (K3=384), gat -> zout + A3 (stride 768)
    {
        gemm_std<<<1024, 256, 0, stream>>>(A3, W3all + 1 * 196608, XLb, XRf, 384, 256, 9, 3);
        gat256<<<N_NODES, 256, 0, stream>>>(row_ptr, ssrc, XLb, XRf, att[1], bia[1], zout, A3);
    }
    // ---- layers 2+3 fused (both read l1's A3): one gemm N2=512 (two slabs), dual gat
    {
        gemm_std<<<1024, 256, 0, stream>>>(A3, W3all + 2 * 196608, XLb, XRf, 768, 128, 8, 3);
        GatP g2{att[2], bia[2], nullptr, nullptr, Rb, XLb, XRf};
        GatP g3{att[3], bia[3], nullptr, A3, nullptr, XLb + (size_t)N_NODES * 128, XRf + (size_t)N_NODES * 128};
        gat128<<<2 * N_NODES, 256, 0, stream>>>(row_ptr, ssrc, g2, g3);
    }
    // ---- layer 4 gemm + recon half A (independent: recon reads Rb, gemm reads A3)
    gemm_recon<<<1024 + 4128, 256, 0, stream>>>(A3, W3all + 4 * 196608, XLb, XRf, 384, 256, 9,
                                                Rb, recon, 0);
    // ---- layer 4 gat + recon half B
    gat256_recon<<<N_NODES + 4128, 256, 0, stream>>>(row_ptr, ssrc, XLb, XRf, att[4], bia[4],
                                                     xrec, Rb, recon, 4128);
}